// Round 1
// baseline (418.068 us; speedup 1.0000x reference)
//
#include <hip/hip_runtime.h>
#include <hip/hip_fp16.h>
#include <math.h>

typedef _Float16 half_t;
typedef _Float16 h8_t __attribute__((ext_vector_type(8)));
typedef _Float16 h4_t __attribute__((ext_vector_type(4)));
typedef float f4_t __attribute__((ext_vector_type(4)));

#define MFMA16(a, b, c) __builtin_amdgcn_mfma_f32_16x16x32_f16(a, b, c, 0, 0, 0)

static constexpr int kB = 4;
static constexpr int kS = 2048;
static constexpr int kD = 1024;
static constexpr int BM = 128;
static constexpr int BN = 128;
static constexpr int BK = 32;  // linear LDS leading dim (halves): 64B rows, lane-contiguous

// ---------- async 16B global->LDS (gfx950 direct-to-LDS path) ----------
__device__ __forceinline__ void gload16(const half_t* g, half_t* l) {
  __builtin_amdgcn_global_load_lds(
      (const __attribute__((address_space(1))) void*)g,
      (__attribute__((address_space(3))) void*)l, 16, 0, 0);
}

// ---------- stage one BMxBK fp16 tile (row-major, ld elems) into LDS [BM][BK] ----------
// Lane l of wave w covers row 16w + (l>>2), col (l&3)*8 -> LDS dest is exactly
// wave_base + l*16B (global_load_lds requirement: wave-uniform base + lane*size).
__device__ __forceinline__ void stage_tile(half_t* __restrict__ sm,
                                           const half_t* __restrict__ g, int ld) {
  const int t = threadIdx.x;
  const int r = t >> 2;
  const int c = (t & 3) * 8;
  gload16(&g[(size_t)r * ld + c], &sm[r * BK + c]);
  gload16(&g[(size_t)(r + 64) * ld + c], &sm[(r + 64) * BK + c]);
}

// ---------- NT GEMM core: C[128,128] += A[128,K] * B[128,K]^T, optional hi/lo split ----------
template <bool SPLIT>
__device__ __forceinline__ void gemm_core(const half_t* __restrict__ Ahi,
                                          const half_t* __restrict__ Alo, int lda,
                                          const half_t* __restrict__ Bhi,
                                          const half_t* __restrict__ Blo, int ldb,
                                          int k_iters, half_t* sm, f4_t acc[4][4]) {
  half_t* sAh = sm;
  half_t* sBh = sm + BM * BK;
  half_t* sAl = sm + 2 * BM * BK;
  half_t* sBl = sm + 3 * BM * BK;
  const int lane = threadIdx.x & 63;
  const int wid = threadIdx.x >> 6;
  const int wm = (wid >> 1) * 64;
  const int wn = (wid & 1) * 64;
  const int fr = lane & 15;         // A/B fragment row: m (or n) = lane&15
  const int fk = (lane >> 4) * 8;   // k = quad*8 + j

  for (int kk = 0; kk < k_iters; ++kk) {
    const size_t ko = (size_t)kk * BK;
    stage_tile(sAh, Ahi + ko, lda);
    stage_tile(sBh, Bhi + ko, ldb);
    if (SPLIT) {
      stage_tile(sAl, Alo + ko, lda);
      stage_tile(sBl, Blo + ko, ldb);
    }
    __syncthreads();  // compiler emits s_waitcnt vmcnt(0) before s_barrier
    h8_t a[4], b[4], al[4], bl[4];
#pragma unroll
    for (int i = 0; i < 4; ++i) {
      a[i] = *(h8_t*)&sAh[(wm + i * 16 + fr) * BK + fk];
      b[i] = *(h8_t*)&sBh[(wn + i * 16 + fr) * BK + fk];
      if (SPLIT) {
        al[i] = *(h8_t*)&sAl[(wm + i * 16 + fr) * BK + fk];
        bl[i] = *(h8_t*)&sBl[(wn + i * 16 + fr) * BK + fk];
      }
    }
#pragma unroll
    for (int i = 0; i < 4; ++i)
#pragma unroll
      for (int j = 0; j < 4; ++j) {
        acc[i][j] = MFMA16(a[i], b[j], acc[i][j]);
        if (SPLIT) {
          acc[i][j] = MFMA16(a[i], bl[j], acc[i][j]);
          acc[i][j] = MFMA16(al[i], b[j], acc[i][j]);
        }
      }
    __syncthreads();
  }
}

// ---------- Q = X * WQK^T (split, fp32-accurate), write Qhi/Qlo fp16 split ----------
__global__ __launch_bounds__(256) void gemm_q_kernel(
    const half_t* __restrict__ Xhi, const half_t* __restrict__ Xlo,
    const half_t* __restrict__ Whi, const half_t* __restrict__ Wlo,
    half_t* __restrict__ Qhi, half_t* __restrict__ Qlo) {
  __shared__ half_t sm[4 * BM * BK];
  const size_t arow = (size_t)blockIdx.y * BM;
  const size_t brow = (size_t)blockIdx.x * BN;
  f4_t acc[4][4] = {};
  gemm_core<true>(Xhi + arow * kD, Xlo + arow * kD, kD,
                  Whi + brow * kD, Wlo + brow * kD, kD, kD / BK, sm, acc);
  const int lane = threadIdx.x & 63;
  const int wid = threadIdx.x >> 6;
  const int wm = (wid >> 1) * 64, wn = (wid & 1) * 64;
  const int c16 = lane & 15, r4 = (lane >> 4) * 4;
#pragma unroll
  for (int i = 0; i < 4; ++i)
#pragma unroll
    for (int j = 0; j < 4; ++j)
#pragma unroll
      for (int r = 0; r < 4; ++r) {
        const size_t row = arow + wm + i * 16 + r4 + r;
        const size_t col = brow + wn + j * 16 + c16;
        const float q = acc[i][j][r];
        const half_t qh = (half_t)q;
        const half_t ql = (half_t)(q - (float)qh);
        const size_t idx = row * kD + col;
        Qhi[idx] = qh;
        Qlo[idx] = ql;
      }
}

// ---------- V = X * WOV^T (single-pass fp16), stored transposed: Vt[b][e][t] ----------
__global__ __launch_bounds__(256) void gemm_v_kernel(
    const half_t* __restrict__ Xhi, const half_t* __restrict__ Whi,
    half_t* __restrict__ Vt) {
  __shared__ half_t sm[2 * BM * BK];
  const size_t arow = (size_t)blockIdx.y * BM;
  const size_t brow = (size_t)blockIdx.x * BN;
  f4_t acc[4][4] = {};
  gemm_core<false>(Xhi + arow * kD, nullptr, kD, Whi + brow * kD, nullptr, kD,
                   kD / BK, sm, acc);
  const int lane = threadIdx.x & 63;
  const int wid = threadIdx.x >> 6;
  const int wm = (wid >> 1) * 64, wn = (wid & 1) * 64;
  const int c16 = lane & 15, r4 = (lane >> 4) * 4;
#pragma unroll
  for (int i = 0; i < 4; ++i)
#pragma unroll
    for (int j = 0; j < 4; ++j)
#pragma unroll
      for (int r = 0; r < 4; ++r) {
        const size_t row = arow + wm + i * 16 + r4 + r;  // global 0..8191
        const size_t col = brow + wn + j * 16 + c16;     // e: 0..1023
        const size_t bi = row >> 11;
        const size_t s = row & 2047;
        Vt[bi * (size_t)kD * kS + col * kS + s] = (half_t)acc[i][j][r];
      }
}

// ---------- Sc = 32 * Q * X^T, causal tiles only, raw scores into d_out A region ----------
__global__ __launch_bounds__(256) void gemm_score_kernel(
    const half_t* __restrict__ Qhi, const half_t* __restrict__ Qlo,
    const half_t* __restrict__ Xhi, const half_t* __restrict__ Xlo,
    float* __restrict__ Sc) {
  const int tn = blockIdx.x, tm = blockIdx.y, bi = blockIdx.z;
  if (tn > tm) return;  // fully masked tile: softmax never reads it
  __shared__ half_t sm[4 * BM * BK];
  const size_t arow = (size_t)bi * kS + (size_t)tm * BM;
  const size_t brow = (size_t)bi * kS + (size_t)tn * BN;
  f4_t acc[4][4] = {};
  gemm_core<true>(Qhi + arow * kD, Qlo + arow * kD, kD,
                  Xhi + brow * kD, Xlo + brow * kD, kD, kD / BK, sm, acc);
  float* out = Sc + (size_t)bi * kS * kS;
  const int lane = threadIdx.x & 63;
  const int wid = threadIdx.x >> 6;
  const int wm = (wid >> 1) * 64, wn = (wid & 1) * 64;
  const int c16 = lane & 15, r4 = (lane >> 4) * 4;
#pragma unroll
  for (int i = 0; i < 4; ++i)
#pragma unroll
    for (int j = 0; j < 4; ++j)
#pragma unroll
      for (int r = 0; r < 4; ++r) {
        const int row = tm * BM + wm + i * 16 + r4 + r;
        const int col = tn * BN + wn + j * 16 + c16;
        out[(size_t)row * kS + col] = 32.0f * acc[i][j][r];
      }
}

// ---------- row softmax (causal), in-place on d_out A region + fp16 copy ----------
__global__ __launch_bounds__(256) void softmax_kernel(float* __restrict__ A,
                                                      half_t* __restrict__ Ah) {
  const int rgl = blockIdx.x;  // 0..8191
  const int s = rgl & 2047;
  float* row = A + (size_t)rgl * kS;
  half_t* hrow = Ah + (size_t)rgl * kS;
  const int tid = threadIdx.x;
  const int n = s + 1;
  float v[8];
  float mx = -INFINITY;
#pragma unroll
  for (int i = 0; i < 8; ++i) {
    const int t = tid + i * 256;
    v[i] = (t < n) ? row[t] : -INFINITY;
    mx = fmaxf(mx, v[i]);
  }
  for (int off = 32; off; off >>= 1) mx = fmaxf(mx, __shfl_xor(mx, off));
  __shared__ float red[8];
  const int lane = tid & 63, wid = tid >> 6;
  if (lane == 0) red[wid] = mx;
  __syncthreads();
  if (tid == 0) {
    float m = fmaxf(fmaxf(red[0], red[1]), fmaxf(red[2], red[3]));
    red[4] = m;
  }
  __syncthreads();
  mx = red[4];
  float sum = 0.0f;
#pragma unroll
  for (int i = 0; i < 8; ++i) {
    v[i] = (tid + i * 256 < n) ? __expf(v[i] - mx) : 0.0f;
    sum += v[i];
  }
  for (int off = 32; off; off >>= 1) sum += __shfl_xor(sum, off);
  __syncthreads();
  if (lane == 0) red[wid] = sum;
  __syncthreads();
  if (tid == 0) red[5] = 1.0f / (red[0] + red[1] + red[2] + red[3]);
  __syncthreads();
  const float inv = red[5];
#pragma unroll
  for (int i = 0; i < 8; ++i) {
    const int t = tid + i * 256;
    const float a = v[i] * inv;  // zero for t > s (v[i]==0 there)
    row[t] = a;
    hrow[t] = (half_t)a;
  }
}

// ---------- Y = A * V (causal K range), epilogue Out0 = X + Y ----------
__global__ __launch_bounds__(256) void gemm_y_kernel(
    const half_t* __restrict__ Ah, const half_t* __restrict__ Vt,
    const float* __restrict__ X, float* __restrict__ Out) {
  __shared__ half_t sm[2 * BM * BK];
  const int tn = blockIdx.x, tm = blockIdx.y, bi = blockIdx.z;
  const size_t abase = ((size_t)bi * kS + (size_t)tm * BM) * kS;
  const size_t bbase = ((size_t)bi * kD + (size_t)tn * BN) * kS;
  f4_t acc[4][4] = {};
  gemm_core<false>(Ah + abase, nullptr, kS, Vt + bbase, nullptr, kS,
                   (tm + 1) * BM / BK, sm, acc);
  const size_t obase = (size_t)bi * kS * kD;
  const int lane = threadIdx.x & 63;
  const int wid = threadIdx.x >> 6;
  const int wm = (wid >> 1) * 64, wn = (wid & 1) * 64;
  const int c16 = lane & 15, r4 = (lane >> 4) * 4;
#pragma unroll
  for (int i = 0; i < 4; ++i)
#pragma unroll
    for (int j = 0; j < 4; ++j)
#pragma unroll
      for (int r = 0; r < 4; ++r) {
        const size_t row = (size_t)tm * BM + wm + i * 16 + r4 + r;
        const size_t col = (size_t)tn * BN + wn + j * 16 + c16;
        const size_t idx = obase + row * kD + col;
        Out[idx] = X[idx] + acc[i][j][r];
      }
}

// ---------- fp32 -> fp16 hi/lo split (and hi-only convert) ----------
__global__ __launch_bounds__(256) void split_kernel(const float* __restrict__ x,
                                                    half_t* __restrict__ hi,
                                                    half_t* __restrict__ lo, int n4) {
  const int i = blockIdx.x * 256 + threadIdx.x;
  if (i >= n4) return;
  const float4 v = ((const float4*)x)[i];
  const float vv[4] = {v.x, v.y, v.z, v.w};
  h4_t h, l;
#pragma unroll
  for (int j = 0; j < 4; ++j) {
    const half_t hh = (half_t)vv[j];
    h[j] = hh;
    l[j] = (half_t)(vv[j] - (float)hh);
  }
  ((h4_t*)hi)[i] = h;
  ((h4_t*)lo)[i] = l;
}

__global__ __launch_bounds__(256) void cvt_kernel(const float* __restrict__ x,
                                                  half_t* __restrict__ hi, int n4) {
  const int i = blockIdx.x * 256 + threadIdx.x;
  if (i >= n4) return;
  const float4 v = ((const float4*)x)[i];
  h4_t h;
  h[0] = (half_t)v.x; h[1] = (half_t)v.y; h[2] = (half_t)v.z; h[3] = (half_t)v.w;
  ((h4_t*)hi)[i] = h;
}

extern "C" void kernel_launch(void* const* d_in, const int* in_sizes, int n_in,
                              void* d_out, int out_size, void* d_ws, size_t ws_size,
                              hipStream_t stream) {
  const float* X   = (const float*)d_in[0];
  // d_in[1] = causal mask: deterministic (tril), recomputed on the fly — unused
  const float* WQK = (const float*)d_in[2];
  const float* WOV = (const float*)d_in[3];

  constexpr size_t nX = (size_t)kB * kS * kD;   // 8388608
  constexpr size_t nW = (size_t)kD * kD;        // 1048576
  constexpr size_t nA = (size_t)kB * kS * kS;   // 16777216

  float* out0 = (float*)d_out;        // X + Y
  float* outA = out0 + nX;            // A (also used as raw-score scratch)

  // workspace layout (fp16 elements)
  half_t* ws = (half_t*)d_ws;
  half_t* Xhi = ws; ws += nX;
  half_t* Xlo = ws; ws += nX;
  half_t* Qhi = ws; ws += nX;
  half_t* Qlo = ws; ws += nX;
  half_t* Whi = ws; ws += nW;
  half_t* Wlo = ws; ws += nW;
  half_t* WVh = ws; ws += nW;
  half_t* Vt  = ws; ws += nX;
  half_t* Ah  = ws; ws += nA;
  const size_t need_bytes = (size_t)((char*)ws - (char*)d_ws);
  if (ws_size < need_bytes) return;  // workspace too small: fail loudly (stub output)

  split_kernel<<<(int)(nX / 4 / 256), 256, 0, stream>>>(X, Xhi, Xlo, (int)(nX / 4));
  split_kernel<<<(int)(nW / 4 / 256), 256, 0, stream>>>(WQK, Whi, Wlo, (int)(nW / 4));
  cvt_kernel<<<(int)(nW / 4 / 256), 256, 0, stream>>>(WOV, WVh, (int)(nW / 4));

  gemm_q_kernel<<<dim3(kD / BN, kB * kS / BM), 256, 0, stream>>>(Xhi, Xlo, Whi, Wlo, Qhi, Qlo);
  gemm_v_kernel<<<dim3(kD / BN, kB * kS / BM), 256, 0, stream>>>(Xhi, WVh, Vt);
  gemm_score_kernel<<<dim3(kS / BN, kS / BM, kB), 256, 0, stream>>>(Qhi, Qlo, Xhi, Xlo, outA);
  softmax_kernel<<<kB * kS, 256, 0, stream>>>(outA, Ah);
  gemm_y_kernel<<<dim3(kD / BN, kS / BM, kB), 256, 0, stream>>>(Ah, Vt, X, out0);
}

// Round 2
// 391.468 us; speedup vs baseline: 1.0679x; 1.0679x over previous
//
#include <hip/hip_runtime.h>
#include <hip/hip_fp16.h>
#include <math.h>

typedef _Float16 half_t;
typedef _Float16 h8_t __attribute__((ext_vector_type(8)));
typedef _Float16 h4_t __attribute__((ext_vector_type(4)));
typedef float f4_t __attribute__((ext_vector_type(4)));

#define MFMA16(a, b, c) __builtin_amdgcn_mfma_f32_16x16x32_f16(a, b, c, 0, 0, 0)

static constexpr int kB = 4;
static constexpr int kS = 2048;
static constexpr int kD = 1024;
static constexpr int BM = 128;
static constexpr int BN = 128;
static constexpr int BK = 32;  // linear LDS leading dim (halves): 64B rows, lane-contiguous

// ---------- async 16B global->LDS (gfx950 direct-to-LDS path) ----------
__device__ __forceinline__ void gload16(const half_t* g, half_t* l) {
  __builtin_amdgcn_global_load_lds(
      (const __attribute__((address_space(1))) void*)g,
      (__attribute__((address_space(3))) void*)l, 16, 0, 0);
}

// ---------- stage one BMxBK fp16 tile (row-major, ld elems) into LDS [BM][BK] ----------
// Lane l of wave w covers row 16w + (l>>2), col (l&3)*8 -> LDS dest is exactly
// wave_base + l*16B (global_load_lds requirement: wave-uniform base + lane*size).
__device__ __forceinline__ void stage_tile(half_t* __restrict__ sm,
                                           const half_t* __restrict__ g, int ld) {
  const int t = threadIdx.x;
  const int r = t >> 2;
  const int c = (t & 3) * 8;
  gload16(&g[(size_t)r * ld + c], &sm[r * BK + c]);
  gload16(&g[(size_t)(r + 64) * ld + c], &sm[(r + 64) * BK + c]);
}

template <bool SPLIT>
__device__ __forceinline__ void stage_all(half_t* buf, const half_t* Ahi,
                                          const half_t* Alo, int lda,
                                          const half_t* Bhi, const half_t* Blo,
                                          int ldb, size_t ko) {
  stage_tile(buf, Ahi + ko, lda);
  stage_tile(buf + BM * BK, Bhi + ko, ldb);
  if (SPLIT) {
    stage_tile(buf + 2 * BM * BK, Alo + ko, lda);
    stage_tile(buf + 3 * BM * BK, Blo + ko, ldb);
  }
}

// ---------- NT GEMM core, 2-phase double-buffered (T3-minimum recipe) ----------
// C[128,128] += A[128,K] * B[128,K]^T, optional hi/lo split (3-term product).
// Prefetch next K-tile via global_load_lds BEFORE computing current tile; raw
// s_barrier + inline vmcnt(0) so the prefetch stays in flight during MFMA
// (__syncthreads would drain vmcnt before the compute phase).
template <bool SPLIT>
__device__ __forceinline__ void gemm_core(const half_t* __restrict__ Ahi,
                                          const half_t* __restrict__ Alo, int lda,
                                          const half_t* __restrict__ Bhi,
                                          const half_t* __restrict__ Blo, int ldb,
                                          int k_iters, half_t* sm, f4_t acc[4][4]) {
  constexpr int BUFSZ = (SPLIT ? 4 : 2) * BM * BK;
  const int lane = threadIdx.x & 63;
  const int wid = threadIdx.x >> 6;
  const int wm = (wid >> 1) * 64;
  const int wn = (wid & 1) * 64;
  const int fr = lane & 15;         // A/B fragment row: m (or n) = lane&15
  const int fk = (lane >> 4) * 8;   // k = quad*8 + j

  half_t* cur = sm;
  half_t* nxt = sm + BUFSZ;

  stage_all<SPLIT>(cur, Ahi, Alo, lda, Bhi, Blo, ldb, 0);
  asm volatile("s_waitcnt vmcnt(0)" ::: "memory");
  __builtin_amdgcn_s_barrier();

  for (int kk = 0; kk < k_iters; ++kk) {
    if (kk + 1 < k_iters)
      stage_all<SPLIT>(nxt, Ahi, Alo, lda, Bhi, Blo, ldb, (size_t)(kk + 1) * BK);
    const half_t* sAh = cur;
    const half_t* sBh = cur + BM * BK;
    const half_t* sAl = cur + 2 * BM * BK;
    const half_t* sBl = cur + 3 * BM * BK;
    h8_t a[4], b[4], al[4], bl[4];
#pragma unroll
    for (int i = 0; i < 4; ++i) {
      a[i] = *(const h8_t*)&sAh[(wm + i * 16 + fr) * BK + fk];
      b[i] = *(const h8_t*)&sBh[(wn + i * 16 + fr) * BK + fk];
      if (SPLIT) {
        al[i] = *(const h8_t*)&sAl[(wm + i * 16 + fr) * BK + fk];
        bl[i] = *(const h8_t*)&sBl[(wn + i * 16 + fr) * BK + fk];
      }
    }
#pragma unroll
    for (int i = 0; i < 4; ++i)
#pragma unroll
      for (int j = 0; j < 4; ++j) {
        acc[i][j] = MFMA16(a[i], b[j], acc[i][j]);
        if (SPLIT) {
          acc[i][j] = MFMA16(a[i], bl[j], acc[i][j]);
          acc[i][j] = MFMA16(al[i], b[j], acc[i][j]);
        }
      }
    // drain the prefetch (only its residual latency is exposed), then swap
    asm volatile("s_waitcnt vmcnt(0)" ::: "memory");
    __builtin_amdgcn_s_barrier();
    half_t* t = cur; cur = nxt; nxt = t;
  }
}

// ---------- Q = X * WQK^T (split, fp32-accurate), write Qhi/Qlo fp16 split ----------
__global__ __launch_bounds__(256) void gemm_q_kernel(
    const half_t* __restrict__ Xhi, const half_t* __restrict__ Xlo,
    const half_t* __restrict__ Whi, const half_t* __restrict__ Wlo,
    half_t* __restrict__ Qhi, half_t* __restrict__ Qlo) {
  __shared__ half_t sm[2 * 4 * BM * BK];  // 64 KB: double-buffered split tiles
  const size_t arow = (size_t)blockIdx.y * BM;
  const size_t brow = (size_t)blockIdx.x * BN;
  f4_t acc[4][4] = {};
  gemm_core<true>(Xhi + arow * kD, Xlo + arow * kD, kD,
                  Whi + brow * kD, Wlo + brow * kD, kD, kD / BK, sm, acc);
  const int lane = threadIdx.x & 63;
  const int wid = threadIdx.x >> 6;
  const int wm = (wid >> 1) * 64, wn = (wid & 1) * 64;
  const int c16 = lane & 15, r4 = (lane >> 4) * 4;
#pragma unroll
  for (int i = 0; i < 4; ++i)
#pragma unroll
    for (int j = 0; j < 4; ++j)
#pragma unroll
      for (int r = 0; r < 4; ++r) {
        const size_t row = arow + wm + i * 16 + r4 + r;
        const size_t col = brow + wn + j * 16 + c16;
        const float q = acc[i][j][r];
        const half_t qh = (half_t)q;
        const half_t ql = (half_t)(q - (float)qh);
        const size_t idx = row * kD + col;
        Qhi[idx] = qh;
        Qlo[idx] = ql;
      }
}

// ---------- V = X * WOV^T (single-pass fp16), stored transposed: Vt[b][e][t] ----------
__global__ __launch_bounds__(256) void gemm_v_kernel(
    const half_t* __restrict__ Xhi, const half_t* __restrict__ Whi,
    half_t* __restrict__ Vt) {
  __shared__ half_t sm[2 * 2 * BM * BK];  // 32 KB double-buffered
  const size_t arow = (size_t)blockIdx.y * BM;
  const size_t brow = (size_t)blockIdx.x * BN;
  f4_t acc[4][4] = {};
  gemm_core<false>(Xhi + arow * kD, nullptr, kD, Whi + brow * kD, nullptr, kD,
                   kD / BK, sm, acc);
  const int lane = threadIdx.x & 63;
  const int wid = threadIdx.x >> 6;
  const int wm = (wid >> 1) * 64, wn = (wid & 1) * 64;
  const int c16 = lane & 15, r4 = (lane >> 4) * 4;
#pragma unroll
  for (int i = 0; i < 4; ++i)
#pragma unroll
    for (int j = 0; j < 4; ++j)
#pragma unroll
      for (int r = 0; r < 4; ++r) {
        const size_t row = arow + wm + i * 16 + r4 + r;  // global 0..8191
        const size_t col = brow + wn + j * 16 + c16;     // e: 0..1023
        const size_t bi = row >> 11;
        const size_t s = row & 2047;
        Vt[bi * (size_t)kD * kS + col * kS + s] = (half_t)acc[i][j][r];
      }
}

// ---------- Sc = 32 * Q * X^T, causal tiles only, raw scores into d_out A region ----------
__global__ __launch_bounds__(256) void gemm_score_kernel(
    const half_t* __restrict__ Qhi, const half_t* __restrict__ Qlo,
    const half_t* __restrict__ Xhi, const half_t* __restrict__ Xlo,
    float* __restrict__ Sc) {
  const int tn = blockIdx.x, tm = blockIdx.y, bi = blockIdx.z;
  if (tn > tm) return;  // fully masked tile: softmax never reads it
  __shared__ half_t sm[2 * 4 * BM * BK];  // 64 KB
  const size_t arow = (size_t)bi * kS + (size_t)tm * BM;
  const size_t brow = (size_t)bi * kS + (size_t)tn * BN;
  f4_t acc[4][4] = {};
  gemm_core<true>(Qhi + arow * kD, Qlo + arow * kD, kD,
                  Xhi + brow * kD, Xlo + brow * kD, kD, kD / BK, sm, acc);
  float* out = Sc + (size_t)bi * kS * kS;
  const int lane = threadIdx.x & 63;
  const int wid = threadIdx.x >> 6;
  const int wm = (wid >> 1) * 64, wn = (wid & 1) * 64;
  const int c16 = lane & 15, r4 = (lane >> 4) * 4;
#pragma unroll
  for (int i = 0; i < 4; ++i)
#pragma unroll
    for (int j = 0; j < 4; ++j)
#pragma unroll
      for (int r = 0; r < 4; ++r) {
        const int row = tm * BM + wm + i * 16 + r4 + r;
        const int col = tn * BN + wn + j * 16 + c16;
        out[(size_t)row * kS + col] = 32.0f * acc[i][j][r];
      }
}

// ---------- row softmax (causal), in-place on d_out A region + fp16 copy ----------
__global__ __launch_bounds__(256) void softmax_kernel(float* __restrict__ A,
                                                      half_t* __restrict__ Ah) {
  const int rgl = blockIdx.x;  // 0..8191
  const int s = rgl & 2047;
  float* row = A + (size_t)rgl * kS;
  half_t* hrow = Ah + (size_t)rgl * kS;
  const int tid = threadIdx.x;
  const int n = s + 1;
  float v[8];
  float mx = -INFINITY;
#pragma unroll
  for (int i = 0; i < 8; ++i) {
    const int t = tid + i * 256;
    v[i] = (t < n) ? row[t] : -INFINITY;
    mx = fmaxf(mx, v[i]);
  }
  for (int off = 32; off; off >>= 1) mx = fmaxf(mx, __shfl_xor(mx, off));
  __shared__ float red[8];
  const int lane = tid & 63, wid = tid >> 6;
  if (lane == 0) red[wid] = mx;
  __syncthreads();
  if (tid == 0) {
    float m = fmaxf(fmaxf(red[0], red[1]), fmaxf(red[2], red[3]));
    red[4] = m;
  }
  __syncthreads();
  mx = red[4];
  float sum = 0.0f;
#pragma unroll
  for (int i = 0; i < 8; ++i) {
    v[i] = (tid + i * 256 < n) ? __expf(v[i] - mx) : 0.0f;
    sum += v[i];
  }
  for (int off = 32; off; off >>= 1) sum += __shfl_xor(sum, off);
  __syncthreads();
  if (lane == 0) red[wid] = sum;
  __syncthreads();
  if (tid == 0) red[5] = 1.0f / (red[0] + red[1] + red[2] + red[3]);
  __syncthreads();
  const float inv = red[5];
#pragma unroll
  for (int i = 0; i < 8; ++i) {
    const int t = tid + i * 256;
    const float a = v[i] * inv;  // zero for t > s (v[i]==0 there)
    row[t] = a;
    hrow[t] = (half_t)a;
  }
}

// ---------- Y = A * V (causal K range), epilogue Out0 = X + Y ----------
// blockIdx.y is REVERSED into tm so heaviest blocks (largest K range)
// dispatch first -> no straggler tail.
__global__ __launch_bounds__(256) void gemm_y_kernel(
    const half_t* __restrict__ Ah, const half_t* __restrict__ Vt,
    const float* __restrict__ X, float* __restrict__ Out) {
  __shared__ half_t sm[2 * 2 * BM * BK];  // 32 KB
  const int tn = blockIdx.x, bi = blockIdx.z;
  const int tm = (kS / BM - 1) - blockIdx.y;  // heavy-first
  const size_t abase = ((size_t)bi * kS + (size_t)tm * BM) * kS;
  const size_t bbase = ((size_t)bi * kD + (size_t)tn * BN) * kS;
  f4_t acc[4][4] = {};
  gemm_core<false>(Ah + abase, nullptr, kS, Vt + bbase, nullptr, kS,
                   (tm + 1) * BM / BK, sm, acc);
  const size_t obase = (size_t)bi * kS * kD;
  const int lane = threadIdx.x & 63;
  const int wid = threadIdx.x >> 6;
  const int wm = (wid >> 1) * 64, wn = (wid & 1) * 64;
  const int c16 = lane & 15, r4 = (lane >> 4) * 4;
#pragma unroll
  for (int i = 0; i < 4; ++i)
#pragma unroll
    for (int j = 0; j < 4; ++j)
#pragma unroll
      for (int r = 0; r < 4; ++r) {
        const size_t row = (size_t)tm * BM + wm + i * 16 + r4 + r;
        const size_t col = (size_t)tn * BN + wn + j * 16 + c16;
        const size_t idx = obase + row * kD + col;
        Out[idx] = X[idx] + acc[i][j][r];
      }
}

// ---------- fp32 -> fp16 hi/lo split (and hi-only convert) ----------
__global__ __launch_bounds__(256) void split_kernel(const float* __restrict__ x,
                                                    half_t* __restrict__ hi,
                                                    half_t* __restrict__ lo, int n4) {
  const int i = blockIdx.x * 256 + threadIdx.x;
  if (i >= n4) return;
  const float4 v = ((const float4*)x)[i];
  const float vv[4] = {v.x, v.y, v.z, v.w};
  h4_t h, l;
#pragma unroll
  for (int j = 0; j < 4; ++j) {
    const half_t hh = (half_t)vv[j];
    h[j] = hh;
    l[j] = (half_t)(vv[j] - (float)hh);
  }
  ((h4_t*)hi)[i] = h;
  ((h4_t*)lo)[i] = l;
}

__global__ __launch_bounds__(256) void cvt_kernel(const float* __restrict__ x,
                                                  half_t* __restrict__ hi, int n4) {
  const int i = blockIdx.x * 256 + threadIdx.x;
  if (i >= n4) return;
  const float4 v = ((const float4*)x)[i];
  h4_t h;
  h[0] = (half_t)v.x; h[1] = (half_t)v.y; h[2] = (half_t)v.z; h[3] = (half_t)v.w;
  ((h4_t*)hi)[i] = h;
}

extern "C" void kernel_launch(void* const* d_in, const int* in_sizes, int n_in,
                              void* d_out, int out_size, void* d_ws, size_t ws_size,
                              hipStream_t stream) {
  const float* X   = (const float*)d_in[0];
  // d_in[1] = causal mask: deterministic (tril), recomputed on the fly — unused
  const float* WQK = (const float*)d_in[2];
  const float* WOV = (const float*)d_in[3];

  constexpr size_t nX = (size_t)kB * kS * kD;   // 8388608
  constexpr size_t nW = (size_t)kD * kD;        // 1048576
  constexpr size_t nA = (size_t)kB * kS * kS;   // 16777216

  float* out0 = (float*)d_out;        // X + Y
  float* outA = out0 + nX;            // A (also used as raw-score scratch)

  // workspace layout (fp16 elements)
  half_t* ws = (half_t*)d_ws;
  half_t* Xhi = ws; ws += nX;
  half_t* Xlo = ws; ws += nX;
  half_t* Qhi = ws; ws += nX;
  half_t* Qlo = ws; ws += nX;
  half_t* Whi = ws; ws += nW;
  half_t* Wlo = ws; ws += nW;
  half_t* WVh = ws; ws += nW;
  half_t* Vt  = ws; ws += nX;
  half_t* Ah  = ws; ws += nA;
  const size_t need_bytes = (size_t)((char*)ws - (char*)d_ws);
  if (ws_size < need_bytes) return;  // workspace too small: fail loudly (stub output)

  split_kernel<<<(int)(nX / 4 / 256), 256, 0, stream>>>(X, Xhi, Xlo, (int)(nX / 4));
  split_kernel<<<(int)(nW / 4 / 256), 256, 0, stream>>>(WQK, Whi, Wlo, (int)(nW / 4));
  cvt_kernel<<<(int)(nW / 4 / 256), 256, 0, stream>>>(WOV, WVh, (int)(nW / 4));

  gemm_q_kernel<<<dim3(kD / BN, kB * kS / BM), 256, 0, stream>>>(Xhi, Xlo, Whi, Wlo, Qhi, Qlo);
  gemm_v_kernel<<<dim3(kD / BN, kB * kS / BM), 256, 0, stream>>>(Xhi, WVh, Vt);
  gemm_score_kernel<<<dim3(kS / BN, kS / BM, kB), 256, 0, stream>>>(Qhi, Qlo, Xhi, Xlo, outA);
  softmax_kernel<<<kB * kS, 256, 0, stream>>>(outA, Ah);
  gemm_y_kernel<<<dim3(kD / BN, kS / BM, kB), 256, 0, stream>>>(Ah, Vt, X, out0);
}

// Round 3
// 380.038 us; speedup vs baseline: 1.1001x; 1.0301x over previous
//
#include <hip/hip_runtime.h>
#include <hip/hip_fp16.h>
#include <math.h>

typedef _Float16 half_t;
typedef _Float16 h8_t __attribute__((ext_vector_type(8)));
typedef _Float16 h4_t __attribute__((ext_vector_type(4)));
typedef float f4_t __attribute__((ext_vector_type(4)));

#define MFMA16(a, b, c) __builtin_amdgcn_mfma_f32_16x16x32_f16(a, b, c, 0, 0, 0)

static constexpr int kB = 4;
static constexpr int kS = 2048;
static constexpr int kD = 1024;
static constexpr int BM = 128;
static constexpr int BN = 128;
static constexpr int BK = 32;   // LDS leading dim (halves): 64B rows, lane-contiguous
static constexpr int NT = 512;  // 8 waves/block: 64x32 output sub-tile per wave

// ---------- async 16B global->LDS (gfx950 direct-to-LDS path) ----------
__device__ __forceinline__ void gload16(const half_t* g, half_t* l) {
  __builtin_amdgcn_global_load_lds(
      (const __attribute__((address_space(1))) void*)g,
      (__attribute__((address_space(3))) void*)l, 16, 0, 0);
}

// ---------- stage one BMxBK fp16 tile into LDS [BM][BK], bank-swizzled ----------
// 512 threads: thread t covers row r = t>>2, 16B granule (t&3).
// LDS dest stays LINEAR (global_load_lds: wave base + lane*16B); the global
// SOURCE column is XOR-swizzled by ((r>>1)&3) granules, and fragment reads
// apply the same XOR -> rows colliding on a bank group now differ by 8 (2-way
// aliasing = free) instead of 2 (8-way).
__device__ __forceinline__ void stage_tile(half_t* __restrict__ sm,
                                           const half_t* __restrict__ g, int ld) {
  const int t = threadIdx.x;
  const int r = t >> 2;
  const int c = ((t & 3) * 8) ^ ((((r >> 1) & 3)) << 3);  // pre-swizzled source col
  gload16(&g[(size_t)r * ld + c], &sm[r * BK + (t & 3) * 8]);
}

template <bool SPLIT>
__device__ __forceinline__ void stage_all(half_t* buf, const half_t* Ahi,
                                          const half_t* Alo, int lda,
                                          const half_t* Bhi, const half_t* Blo,
                                          int ldb, size_t ko) {
  stage_tile(buf, Ahi + ko, lda);
  stage_tile(buf + BM * BK, Bhi + ko, ldb);
  if (SPLIT) {
    stage_tile(buf + 2 * BM * BK, Alo + ko, lda);
    stage_tile(buf + 3 * BM * BK, Blo + ko, ldb);
  }
}

// ---------- NT GEMM core, 8-wave, 2-phase double-buffered ----------
// C[128,128] += A[128,K] * B[128,K]^T, optional hi/lo split (3-term product).
// Wave wid owns rows [(wid>>2)*64, +64) x cols [(wid&3)*32, +32): acc[4][2].
template <bool SPLIT>
__device__ __forceinline__ void gemm_core(const half_t* __restrict__ Ahi,
                                          const half_t* __restrict__ Alo, int lda,
                                          const half_t* __restrict__ Bhi,
                                          const half_t* __restrict__ Blo, int ldb,
                                          int k_iters, half_t* sm, f4_t acc[4][2]) {
  constexpr int BUFSZ = (SPLIT ? 4 : 2) * BM * BK;
  const int lane = threadIdx.x & 63;
  const int wid = threadIdx.x >> 6;        // 0..7
  const int wm = (wid >> 2) * 64;          // 0, 64
  const int wn = (wid & 3) * 32;           // 0, 32, 64, 96
  const int fr = lane & 15;                                  // fragment row
  const int fk = (((lane >> 4) * 8) ^ (((lane >> 1) & 3) << 3));  // swizzled k-offset

  half_t* cur = sm;
  half_t* nxt = sm + BUFSZ;

  stage_all<SPLIT>(cur, Ahi, Alo, lda, Bhi, Blo, ldb, 0);
  asm volatile("s_waitcnt vmcnt(0)" ::: "memory");
  __builtin_amdgcn_s_barrier();

  for (int kk = 0; kk < k_iters; ++kk) {
    if (kk + 1 < k_iters)
      stage_all<SPLIT>(nxt, Ahi, Alo, lda, Bhi, Blo, ldb, (size_t)(kk + 1) * BK);
    const half_t* sAh = cur;
    const half_t* sBh = cur + BM * BK;
    const half_t* sAl = cur + 2 * BM * BK;
    const half_t* sBl = cur + 3 * BM * BK;
    h8_t a[4], b[2], al[4], bl[2];
#pragma unroll
    for (int i = 0; i < 4; ++i) {
      a[i] = *(const h8_t*)&sAh[(wm + i * 16 + fr) * BK + fk];
      if (SPLIT) al[i] = *(const h8_t*)&sAl[(wm + i * 16 + fr) * BK + fk];
    }
#pragma unroll
    for (int j = 0; j < 2; ++j) {
      b[j] = *(const h8_t*)&sBh[(wn + j * 16 + fr) * BK + fk];
      if (SPLIT) bl[j] = *(const h8_t*)&sBl[(wn + j * 16 + fr) * BK + fk];
    }
#pragma unroll
    for (int i = 0; i < 4; ++i)
#pragma unroll
      for (int j = 0; j < 2; ++j) {
        acc[i][j] = MFMA16(a[i], b[j], acc[i][j]);
        if (SPLIT) {
          acc[i][j] = MFMA16(a[i], bl[j], acc[i][j]);
          acc[i][j] = MFMA16(al[i], b[j], acc[i][j]);
        }
      }
    // drain the prefetch (only residual latency exposed), then swap buffers
    asm volatile("s_waitcnt vmcnt(0)" ::: "memory");
    __builtin_amdgcn_s_barrier();
    half_t* t = cur; cur = nxt; nxt = t;
  }
}

// ---------- Q = X * WQK^T (split, fp32-accurate), write Qhi/Qlo fp16 split ----------
__global__ __launch_bounds__(NT) void gemm_q_kernel(
    const half_t* __restrict__ Xhi, const half_t* __restrict__ Xlo,
    const half_t* __restrict__ Whi, const half_t* __restrict__ Wlo,
    half_t* __restrict__ Qhi, half_t* __restrict__ Qlo) {
  __shared__ half_t sm[2 * 4 * BM * BK];  // 64 KB: double-buffered split tiles
  const size_t arow = (size_t)blockIdx.y * BM;
  const size_t brow = (size_t)blockIdx.x * BN;
  f4_t acc[4][2] = {};
  gemm_core<true>(Xhi + arow * kD, Xlo + arow * kD, kD,
                  Whi + brow * kD, Wlo + brow * kD, kD, kD / BK, sm, acc);
  const int lane = threadIdx.x & 63;
  const int wid = threadIdx.x >> 6;
  const int wm = (wid >> 2) * 64, wn = (wid & 3) * 32;
  const int c16 = lane & 15, r4 = (lane >> 4) * 4;
#pragma unroll
  for (int i = 0; i < 4; ++i)
#pragma unroll
    for (int j = 0; j < 2; ++j)
#pragma unroll
      for (int r = 0; r < 4; ++r) {
        const size_t row = arow + wm + i * 16 + r4 + r;
        const size_t col = brow + wn + j * 16 + c16;
        const float q = acc[i][j][r];
        const half_t qh = (half_t)q;
        const half_t ql = (half_t)(q - (float)qh);
        const size_t idx = row * kD + col;
        Qhi[idx] = qh;
        Qlo[idx] = ql;
      }
}

// ---------- V = X * WOV^T (single-pass fp16), stored transposed: Vt[b][e][t] ----------
__global__ __launch_bounds__(NT) void gemm_v_kernel(
    const half_t* __restrict__ Xhi, const half_t* __restrict__ Whi,
    half_t* __restrict__ Vt) {
  __shared__ half_t sm[2 * 2 * BM * BK];  // 32 KB double-buffered
  const size_t arow = (size_t)blockIdx.y * BM;
  const size_t brow = (size_t)blockIdx.x * BN;
  f4_t acc[4][2] = {};
  gemm_core<false>(Xhi + arow * kD, nullptr, kD, Whi + brow * kD, nullptr, kD,
                   kD / BK, sm, acc);
  const int lane = threadIdx.x & 63;
  const int wid = threadIdx.x >> 6;
  const int wm = (wid >> 2) * 64, wn = (wid & 3) * 32;
  const int c16 = lane & 15, r4 = (lane >> 4) * 4;
#pragma unroll
  for (int i = 0; i < 4; ++i)
#pragma unroll
    for (int j = 0; j < 2; ++j)
#pragma unroll
      for (int r = 0; r < 4; ++r) {
        const size_t row = arow + wm + i * 16 + r4 + r;  // global 0..8191
        const size_t col = brow + wn + j * 16 + c16;     // e: 0..1023
        const size_t bi = row >> 11;
        const size_t s = row & 2047;
        Vt[bi * (size_t)kD * kS + col * kS + s] = (half_t)acc[i][j][r];
      }
}

// ---------- Sc = 32 * Q * X^T, causal tiles only, raw scores into d_out A region ----------
__global__ __launch_bounds__(NT) void gemm_score_kernel(
    const half_t* __restrict__ Qhi, const half_t* __restrict__ Qlo,
    const half_t* __restrict__ Xhi, const half_t* __restrict__ Xlo,
    float* __restrict__ Sc) {
  const int tn = blockIdx.x, tm = blockIdx.y, bi = blockIdx.z;
  if (tn > tm) return;  // fully masked tile: softmax never reads it
  __shared__ half_t sm[2 * 4 * BM * BK];  // 64 KB
  const size_t arow = (size_t)bi * kS + (size_t)tm * BM;
  const size_t brow = (size_t)bi * kS + (size_t)tn * BN;
  f4_t acc[4][2] = {};
  gemm_core<true>(Qhi + arow * kD, Qlo + arow * kD, kD,
                  Xhi + brow * kD, Xlo + brow * kD, kD, kD / BK, sm, acc);
  float* out = Sc + (size_t)bi * kS * kS;
  const int lane = threadIdx.x & 63;
  const int wid = threadIdx.x >> 6;
  const int wm = (wid >> 2) * 64, wn = (wid & 3) * 32;
  const int c16 = lane & 15, r4 = (lane >> 4) * 4;
#pragma unroll
  for (int i = 0; i < 4; ++i)
#pragma unroll
    for (int j = 0; j < 2; ++j)
#pragma unroll
      for (int r = 0; r < 4; ++r) {
        const int row = tm * BM + wm + i * 16 + r4 + r;
        const int col = tn * BN + wn + j * 16 + c16;
        out[(size_t)row * kS + col] = 32.0f * acc[i][j][r];
      }
}

// ---------- row softmax (causal), in-place on d_out A region + fp16 copy ----------
__global__ __launch_bounds__(256) void softmax_kernel(float* __restrict__ A,
                                                      half_t* __restrict__ Ah) {
  const int rgl = blockIdx.x;  // 0..8191
  const int s = rgl & 2047;
  float* row = A + (size_t)rgl * kS;
  half_t* hrow = Ah + (size_t)rgl * kS;
  const int tid = threadIdx.x;
  const int n = s + 1;
  float v[8];
  float mx = -INFINITY;
#pragma unroll
  for (int i = 0; i < 8; ++i) {
    const int t = tid + i * 256;
    v[i] = (t < n) ? row[t] : -INFINITY;
    mx = fmaxf(mx, v[i]);
  }
  for (int off = 32; off; off >>= 1) mx = fmaxf(mx, __shfl_xor(mx, off));
  __shared__ float red[8];
  const int lane = tid & 63, wid = tid >> 6;
  if (lane == 0) red[wid] = mx;
  __syncthreads();
  if (tid == 0) {
    float m = fmaxf(fmaxf(red[0], red[1]), fmaxf(red[2], red[3]));
    red[4] = m;
  }
  __syncthreads();
  mx = red[4];
  float sum = 0.0f;
#pragma unroll
  for (int i = 0; i < 8; ++i) {
    v[i] = (tid + i * 256 < n) ? __expf(v[i] - mx) : 0.0f;
    sum += v[i];
  }
  for (int off = 32; off; off >>= 1) sum += __shfl_xor(sum, off);
  __syncthreads();
  if (lane == 0) red[wid] = sum;
  __syncthreads();
  if (tid == 0) red[5] = 1.0f / (red[0] + red[1] + red[2] + red[3]);
  __syncthreads();
  const float inv = red[5];
#pragma unroll
  for (int i = 0; i < 8; ++i) {
    const int t = tid + i * 256;
    const float a = v[i] * inv;  // zero for t > s (v[i]==0 there)
    row[t] = a;
    hrow[t] = (half_t)a;
  }
}

// ---------- Y = A * V (causal K range), epilogue Out0 = X + Y ----------
// blockIdx.y is REVERSED into tm so heaviest blocks dispatch first.
__global__ __launch_bounds__(NT) void gemm_y_kernel(
    const half_t* __restrict__ Ah, const half_t* __restrict__ Vt,
    const float* __restrict__ X, float* __restrict__ Out) {
  __shared__ half_t sm[2 * 2 * BM * BK];  // 32 KB
  const int tn = blockIdx.x, bi = blockIdx.z;
  const int tm = (kS / BM - 1) - blockIdx.y;  // heavy-first
  const size_t abase = ((size_t)bi * kS + (size_t)tm * BM) * kS;
  const size_t bbase = ((size_t)bi * kD + (size_t)tn * BN) * kS;
  f4_t acc[4][2] = {};
  gemm_core<false>(Ah + abase, nullptr, kS, Vt + bbase, nullptr, kS,
                   (tm + 1) * BM / BK, sm, acc);
  const size_t obase = (size_t)bi * kS * kD;
  const int lane = threadIdx.x & 63;
  const int wid = threadIdx.x >> 6;
  const int wm = (wid >> 2) * 64, wn = (wid & 3) * 32;
  const int c16 = lane & 15, r4 = (lane >> 4) * 4;
#pragma unroll
  for (int i = 0; i < 4; ++i)
#pragma unroll
    for (int j = 0; j < 2; ++j)
#pragma unroll
      for (int r = 0; r < 4; ++r) {
        const size_t row = (size_t)tm * BM + wm + i * 16 + r4 + r;
        const size_t col = (size_t)tn * BN + wn + j * 16 + c16;
        const size_t idx = obase + row * kD + col;
        Out[idx] = X[idx] + acc[i][j][r];
      }
}

// ---------- fp32 -> fp16 hi/lo split (and hi-only convert) ----------
__global__ __launch_bounds__(256) void split_kernel(const float* __restrict__ x,
                                                    half_t* __restrict__ hi,
                                                    half_t* __restrict__ lo, int n4) {
  const int i = blockIdx.x * 256 + threadIdx.x;
  if (i >= n4) return;
  const float4 v = ((const float4*)x)[i];
  const float vv[4] = {v.x, v.y, v.z, v.w};
  h4_t h, l;
#pragma unroll
  for (int j = 0; j < 4; ++j) {
    const half_t hh = (half_t)vv[j];
    h[j] = hh;
    l[j] = (half_t)(vv[j] - (float)hh);
  }
  ((h4_t*)hi)[i] = h;
  ((h4_t*)lo)[i] = l;
}

__global__ __launch_bounds__(256) void cvt_kernel(const float* __restrict__ x,
                                                  half_t* __restrict__ hi, int n4) {
  const int i = blockIdx.x * 256 + threadIdx.x;
  if (i >= n4) return;
  const float4 v = ((const float4*)x)[i];
  h4_t h;
  h[0] = (half_t)v.x; h[1] = (half_t)v.y; h[2] = (half_t)v.z; h[3] = (half_t)v.w;
  ((h4_t*)hi)[i] = h;
}

extern "C" void kernel_launch(void* const* d_in, const int* in_sizes, int n_in,
                              void* d_out, int out_size, void* d_ws, size_t ws_size,
                              hipStream_t stream) {
  const float* X   = (const float*)d_in[0];
  // d_in[1] = causal mask: deterministic (tril), recomputed on the fly — unused
  const float* WQK = (const float*)d_in[2];
  const float* WOV = (const float*)d_in[3];

  constexpr size_t nX = (size_t)kB * kS * kD;   // 8388608
  constexpr size_t nW = (size_t)kD * kD;        // 1048576
  constexpr size_t nA = (size_t)kB * kS * kS;   // 16777216

  float* out0 = (float*)d_out;        // X + Y
  float* outA = out0 + nX;            // A (also used as raw-score scratch)

  // workspace layout (fp16 elements)
  half_t* ws = (half_t*)d_ws;
  half_t* Xhi = ws; ws += nX;
  half_t* Xlo = ws; ws += nX;
  half_t* Qhi = ws; ws += nX;
  half_t* Qlo = ws; ws += nX;
  half_t* Whi = ws; ws += nW;
  half_t* Wlo = ws; ws += nW;
  half_t* WVh = ws; ws += nW;
  half_t* Vt  = ws; ws += nX;
  half_t* Ah  = ws; ws += nA;
  const size_t need_bytes = (size_t)((char*)ws - (char*)d_ws);
  if (ws_size < need_bytes) return;  // workspace too small: fail loudly (stub output)

  split_kernel<<<(int)(nX / 4 / 256), 256, 0, stream>>>(X, Xhi, Xlo, (int)(nX / 4));
  split_kernel<<<(int)(nW / 4 / 256), 256, 0, stream>>>(WQK, Whi, Wlo, (int)(nW / 4));
  cvt_kernel<<<(int)(nW / 4 / 256), 256, 0, stream>>>(WOV, WVh, (int)(nW / 4));

  gemm_q_kernel<<<dim3(kD / BN, kB * kS / BM), NT, 0, stream>>>(Xhi, Xlo, Whi, Wlo, Qhi, Qlo);
  gemm_v_kernel<<<dim3(kD / BN, kB * kS / BM), NT, 0, stream>>>(Xhi, WVh, Vt);
  gemm_score_kernel<<<dim3(kS / BN, kS / BM, kB), NT, 0, stream>>>(Qhi, Qlo, Xhi, Xlo, outA);
  softmax_kernel<<<kB * kS, 256, 0, stream>>>(outA, Ah);
  gemm_y_kernel<<<dim3(kD / BN, kS / BM, kB), NT, 0, stream>>>(Ah, Vt, X, out0);
}